// Round 1
// baseline (2386.707 us; speedup 1.0000x reference)
//
#include <hip/hip_runtime.h>
#include <hip/hip_bf16.h>
#include <math.h>

// Problem constants
#define BSZ 8
#define LSEQ 512
#define ENC_IN 7
#define D_MODEL 768
#define D_INNER 1536
#define DT_RANK 48
#define N_STATE 16
#define K_CONV 4
#define E_LAYERS 2
#define C_OUT 7
#define PRED_LEN 96
#define EPSV 1e-5f

#define ROWS (BSZ*LSEQ)            // 4096

// ---------------------------------------------------------------- utilities
__device__ __forceinline__ float block_sum(float v, float* tmp /*>=4 floats*/) {
    // blockDim.x == 256 (4 waves of 64)
    #pragma unroll
    for (int off = 32; off > 0; off >>= 1) v += __shfl_down(v, off);
    int lane = threadIdx.x & 63, wid = threadIdx.x >> 6;
    __syncthreads();
    if (lane == 0) tmp[wid] = v;
    __syncthreads();
    return tmp[0] + tmp[1] + tmp[2] + tmp[3];
}

// ---------------------------------------------------------------- stats (RevIN)
__global__ __launch_bounds__(256) void stats_kernel(const float* __restrict__ x,
                                                    float* __restrict__ mean,
                                                    float* __restrict__ stdv) {
    int bc = blockIdx.x;              // 0..55
    int b = bc / ENC_IN, c = bc % ENC_IN;
    __shared__ float tmp[4];
    float s = 0.f, sq = 0.f;
    for (int l = threadIdx.x; l < LSEQ; l += 256) {
        float v = x[((size_t)(b*LSEQ + l))*ENC_IN + c];
        s += v; sq += v*v;
    }
    s = block_sum(s, tmp);
    sq = block_sum(sq, tmp);
    if (threadIdx.x == 0) {
        float m = s / LSEQ;
        float var = sq / LSEQ - m*m;
        if (var < 0.f) var = 0.f;
        mean[bc] = m;
        stdv[bc] = sqrtf(var + EPSV);
    }
}

// ---------------------------------------------------------------- embedding
// h[b,l,d] = tokenConv(xc)[b,l,d] + PE[l,d] + (l/L)*time_w[d]
__global__ __launch_bounds__(256) void embed_kernel(const float* __restrict__ x,
                                                    const float* __restrict__ token_w,
                                                    const float* __restrict__ time_w,
                                                    const float* __restrict__ mean,
                                                    const float* __restrict__ stdv,
                                                    float* __restrict__ h) {
    int bl = blockIdx.x;              // b*512+l
    int b = bl >> 9, l = bl & 511;
    __shared__ float sxc[ENC_IN*3];   // xc[(l+k-1) mod 512, c] for k=0..2
    if (threadIdx.x < ENC_IN*3) {
        int c = threadIdx.x / 3, k = threadIdx.x % 3;
        int lk = (l + k - 1) & 511;
        float v = x[((size_t)(b*LSEQ + lk))*ENC_IN + c];
        sxc[threadIdx.x] = (v - mean[b*ENC_IN + c]) / stdv[b*ENC_IN + c];
    }
    __syncthreads();
    #pragma unroll
    for (int i = 0; i < 3; i++) {
        int d = threadIdx.x + i*256;
        float acc = 0.f;
        const float* w = token_w + (size_t)d*21;
        #pragma unroll
        for (int t = 0; t < 21; t++) acc += sxc[t] * w[t];
        // positional embedding
        int d2 = d & ~1;
        float div = __expf((float)d2 * (-9.210340371976184f / (float)D_MODEL));
        float ang = (float)l * div;
        float pe = (d & 1) ? cosf(ang) : sinf(ang);
        // time embedding
        float tm = ((float)l / (float)LSEQ) * time_w[d];
        h[(size_t)bl*D_MODEL + d] = acc + pe + tm;
    }
}

// ---------------------------------------------------------------- rmsnorm
__global__ __launch_bounds__(256) void rmsnorm_kernel(const float* __restrict__ h,
                                                      const float* __restrict__ w,
                                                      float* __restrict__ xn) {
    size_t base = (size_t)blockIdx.x * D_MODEL;
    __shared__ float tmp[4];
    float ss = 0.f;
    for (int k = threadIdx.x; k < D_MODEL; k += 256) { float v = h[base+k]; ss += v*v; }
    ss = block_sum(ss, tmp);
    float inv = rsqrtf(ss / (float)D_MODEL + EPSV);
    for (int k = threadIdx.x; k < D_MODEL; k += 256) xn[base+k] = h[base+k]*inv*w[k];
}

// ---------------------------------------------------------------- generic fp32 GEMM: C = A(M,K;lda) @ W(N,K)^T
// FUSE 0: plain   FUSE 1: softplus(acc + bias[n])   FUSE 2: acc + res[m*ldr+n]
#define BM 64
#define BN 64
#define BKT 16
template<int FUSE>
__global__ __launch_bounds__(256) void gemm_nt(const float* __restrict__ A, int lda,
                                               const float* __restrict__ W,
                                               float* __restrict__ C, int ldc,
                                               int M, int N, int K,
                                               const float* __restrict__ bias,
                                               const float* __restrict__ res, int ldr) {
    __shared__ float As[BKT][BM+4];
    __shared__ float Ws[BKT][BN+4];
    int tid = threadIdx.x;
    int tx = tid & 15, ty = tid >> 4;
    int m0 = blockIdx.y * BM, n0 = blockIdx.x * BN;
    float acc[4][4] = {};
    for (int k0 = 0; k0 < K; k0 += BKT) {
        #pragma unroll
        for (int i = 0; i < 4; i++) {
            int idx = tid + i*256;
            int r = idx >> 4, c = idx & 15;
            int m = m0 + r, k = k0 + c;
            As[c][r] = (m < M && k < K) ? A[(size_t)m*lda + k] : 0.f;
            int n = n0 + r;
            Ws[c][r] = (n < N && k < K) ? W[(size_t)n*K + k] : 0.f;
        }
        __syncthreads();
        #pragma unroll
        for (int k = 0; k < BKT; k++) {
            float4 a = *(const float4*)&As[k][ty*4];
            float4 b = *(const float4*)&Ws[k][tx*4];
            float av[4] = {a.x,a.y,a.z,a.w};
            float bv[4] = {b.x,b.y,b.z,b.w};
            #pragma unroll
            for (int i = 0; i < 4; i++)
                #pragma unroll
                for (int j = 0; j < 4; j++)
                    acc[i][j] += av[i]*bv[j];
        }
        __syncthreads();
    }
    #pragma unroll
    for (int i = 0; i < 4; i++) {
        int m = m0 + ty*4 + i; if (m >= M) continue;
        #pragma unroll
        for (int j = 0; j < 4; j++) {
            int n = n0 + tx*4 + j; if (n >= N) continue;
            float v = acc[i][j];
            if (FUSE == 1) { v += bias[n]; v = fmaxf(v, 0.f) + log1pf(__expf(-fabsf(v))); }
            if (FUSE == 2) { v += res[(size_t)m*ldr + n]; }
            C[(size_t)m*ldc + n] = v;
        }
    }
}

// ---------------------------------------------------------------- depthwise causal conv + SiLU
__global__ __launch_bounds__(256) void dwconv_silu(const float* __restrict__ xr,
                                                   const float* __restrict__ cw,
                                                   const float* __restrict__ cb,
                                                   float* __restrict__ u) {
    int idx = blockIdx.x*256 + threadIdx.x;
    if (idx >= ROWS*D_INNER) return;
    int d = idx % D_INNER;
    int t = idx / D_INNER;
    int l = t & 511, b = t >> 9;
    float acc = cb[d];
    #pragma unroll
    for (int k = 0; k < K_CONV; k++) {
        int ll = l - (K_CONV-1) + k;
        if (ll >= 0) acc += xr[((size_t)(b*LSEQ + ll))*(2*D_INNER) + d] * cw[d*K_CONV + k];
    }
    u[(size_t)t*D_INNER + d] = acc / (1.f + __expf(-acc));
}

// ---------------------------------------------------------------- selective scan (+ gate fuse)
// thread layout: 16 threads per (b,d) channel, one per state n.
// writes y*silu(res) into xr[:, :D_INNER] (first half), reading res from second half.
__global__ __launch_bounds__(256) void scan_kernel(const float* __restrict__ u,
                                                   const float* __restrict__ delta,
                                                   const float* __restrict__ xdbl,
                                                   const float* __restrict__ A_log,
                                                   const float* __restrict__ Dp,
                                                   float* __restrict__ xr) {
    int g = threadIdx.x >> 4;         // 0..15 channel group in block
    int n = threadIdx.x & 15;         // state index
    int d = blockIdx.x*16 + g;        // 0..1535
    int b = blockIdx.y;               // 0..7
    float A = -__expf(A_log[d*N_STATE + n]);
    float Dv = Dp[d];
    float xs = 0.f;
    for (int l = 0; l < LSEQ; l++) {
        size_t base = (size_t)(b*LSEQ + l);
        float dlt = delta[base*D_INNER + d];
        float uu  = u[base*D_INNER + d];
        float Bn  = xdbl[base*80 + DT_RANK + n];
        float Cn  = xdbl[base*80 + DT_RANK + N_STATE + n];
        xs = __expf(dlt*A)*xs + dlt*uu*Bn;
        float c = xs * Cn;
        c += __shfl_xor(c, 1);
        c += __shfl_xor(c, 2);
        c += __shfl_xor(c, 4);
        c += __shfl_xor(c, 8);
        if (n == 0) {
            float y = c + uu*Dv;
            float r = xr[base*(2*D_INNER) + D_INNER + d];
            xr[base*(2*D_INNER) + d] = y * (r / (1.f + __expf(-r)));
        }
    }
}

// ---------------------------------------------------------------- final norm + head + de-norm
__global__ __launch_bounds__(256) void final_kernel(const float* __restrict__ h,
                                                    const float* __restrict__ fnw,
                                                    const float* __restrict__ out_w,
                                                    const float* __restrict__ mean,
                                                    const float* __restrict__ stdv,
                                                    float* __restrict__ out) {
    int bid = blockIdx.x;             // 0..767
    int b = bid / PRED_LEN, lo = bid % PRED_LEN;
    int l = LSEQ - PRED_LEN + lo;
    const float* row = h + ((size_t)(b*LSEQ + l))*D_MODEL;
    __shared__ float tmp[4];
    float ss = 0.f;
    for (int k = threadIdx.x; k < D_MODEL; k += 256) { float v = row[k]; ss += v*v; }
    ss = block_sum(ss, tmp);
    float inv = rsqrtf(ss / (float)D_MODEL + EPSV);
    float acc[C_OUT] = {};
    for (int k = threadIdx.x; k < D_MODEL; k += 256) {
        float hn = row[k]*fnw[k];
        #pragma unroll
        for (int c = 0; c < C_OUT; c++) acc[c] += hn*out_w[c*D_MODEL + k];
    }
    #pragma unroll
    for (int c = 0; c < C_OUT; c++) {
        float s = block_sum(acc[c], tmp);
        if (threadIdx.x == 0)
            out[((size_t)(b*PRED_LEN + lo))*C_OUT + c] = s*inv*stdv[b*ENC_IN + c] + mean[b*ENC_IN + c];
    }
}

// ---------------------------------------------------------------- launch
extern "C" void kernel_launch(void* const* d_in, const int* in_sizes, int n_in,
                              void* d_out, int out_size, void* d_ws, size_t ws_size,
                              hipStream_t stream) {
    const float* x        = (const float*)d_in[0];
    const float* token_w  = (const float*)d_in[1];
    const float* time_w   = (const float*)d_in[2];
    const float* norm_w   = (const float*)d_in[3];
    const float* in_w     = (const float*)d_in[4];
    const float* conv_w   = (const float*)d_in[5];
    const float* conv_b   = (const float*)d_in[6];
    const float* xproj_w  = (const float*)d_in[7];
    const float* dtproj_w = (const float*)d_in[8];
    const float* dtproj_b = (const float*)d_in[9];
    const float* A_log    = (const float*)d_in[10];
    const float* Dp       = (const float*)d_in[11];
    const float* outproj_w= (const float*)d_in[12];
    const float* final_nw = (const float*)d_in[13];
    const float* out_w    = (const float*)d_in[14];
    float* out = (float*)d_out;

    float* ws   = (float*)d_ws;
    float* mean = ws;                         // 56
    float* stdv = ws + 64;                    // 56
    float* h    = ws + 128;                   // 4096*768
    float* xn   = h    + (size_t)ROWS*D_MODEL;
    float* xr   = xn   + (size_t)ROWS*D_MODEL;      // 4096*3072
    float* u    = xr   + (size_t)ROWS*2*D_INNER;    // 4096*1536
    float* xdbl = u    + (size_t)ROWS*D_INNER;      // 4096*80
    float* delta= xdbl + (size_t)ROWS*80;           // 4096*1536
    // total ~127 MB of f32 workspace

    stats_kernel<<<BSZ*ENC_IN, 256, 0, stream>>>(x, mean, stdv);
    embed_kernel<<<ROWS, 256, 0, stream>>>(x, token_w, time_w, mean, stdv, h);

    for (int e = 0; e < E_LAYERS; e++) {
        rmsnorm_kernel<<<ROWS, 256, 0, stream>>>(h, norm_w + e*D_MODEL, xn);
        gemm_nt<0><<<dim3(2*D_INNER/BN, ROWS/BM), 256, 0, stream>>>(
            xn, D_MODEL, in_w + (size_t)e*2*D_INNER*D_MODEL, xr, 2*D_INNER,
            ROWS, 2*D_INNER, D_MODEL, nullptr, nullptr, 0);
        dwconv_silu<<<(ROWS*D_INNER + 255)/256, 256, 0, stream>>>(
            xr, conv_w + (size_t)e*D_INNER*K_CONV, conv_b + e*D_INNER, u);
        gemm_nt<0><<<dim3((80 + BN-1)/BN, ROWS/BM), 256, 0, stream>>>(
            u, D_INNER, xproj_w + (size_t)e*80*D_INNER, xdbl, 80,
            ROWS, 80, D_INNER, nullptr, nullptr, 0);
        gemm_nt<1><<<dim3(D_INNER/BN, ROWS/BM), 256, 0, stream>>>(
            xdbl, 80, dtproj_w + (size_t)e*D_INNER*DT_RANK, delta, D_INNER,
            ROWS, D_INNER, DT_RANK, dtproj_b + e*D_INNER, nullptr, 0);
        scan_kernel<<<dim3(D_INNER/16, BSZ), 256, 0, stream>>>(
            u, delta, xdbl, A_log + (size_t)e*D_INNER*N_STATE, Dp + e*D_INNER, xr);
        gemm_nt<2><<<dim3(D_MODEL/BN, ROWS/BM), 256, 0, stream>>>(
            xr, 2*D_INNER, outproj_w + (size_t)e*D_MODEL*D_INNER, h, D_MODEL,
            ROWS, D_MODEL, D_INNER, nullptr, h, D_MODEL);
    }

    final_kernel<<<BSZ*PRED_LEN, 256, 0, stream>>>(h, final_nw, out_w, mean, stdv, out);
}

// Round 2
// 868.461 us; speedup vs baseline: 2.7482x; 2.7482x over previous
//
#include <hip/hip_runtime.h>
#include <hip/hip_bf16.h>
#include <math.h>

// Problem constants
#define BSZ 8
#define LSEQ 512
#define ENC_IN 7
#define D_MODEL 768
#define D_INNER 1536
#define DT_RANK 48
#define N_STATE 16
#define K_CONV 4
#define E_LAYERS 2
#define C_OUT 7
#define PRED_LEN 96
#define EPSV 1e-5f

#define ROWS (BSZ*LSEQ)            // 4096
#define NC 8                       // scan chunks
#define CL (LSEQ/NC)               // 64 steps per chunk

typedef __bf16 bf16x8 __attribute__((ext_vector_type(8)));
typedef float  f32x4  __attribute__((ext_vector_type(4)));

// ---------------------------------------------------------------- utilities
__device__ __forceinline__ float block_sum(float v, float* tmp) {
    #pragma unroll
    for (int off = 32; off > 0; off >>= 1) v += __shfl_down(v, off);
    int lane = threadIdx.x & 63, wid = threadIdx.x >> 6;
    __syncthreads();
    if (lane == 0) tmp[wid] = v;
    __syncthreads();
    return tmp[0] + tmp[1] + tmp[2] + tmp[3];
}

// ---------------------------------------------------------------- f32 -> bf16 convert
__global__ __launch_bounds__(256) void cvt_bf16(const float* __restrict__ in,
                                                __hip_bfloat16* __restrict__ out, int n) {
    int i = blockIdx.x*256 + threadIdx.x;
    if (i < n) out[i] = __float2bfloat16(in[i]);
}

// ---------------------------------------------------------------- stats (RevIN)
__global__ __launch_bounds__(256) void stats_kernel(const float* __restrict__ x,
                                                    float* __restrict__ mean,
                                                    float* __restrict__ stdv) {
    int bc = blockIdx.x;
    int b = bc / ENC_IN, c = bc % ENC_IN;
    __shared__ float tmp[4];
    float s = 0.f, sq = 0.f;
    for (int l = threadIdx.x; l < LSEQ; l += 256) {
        float v = x[((size_t)(b*LSEQ + l))*ENC_IN + c];
        s += v; sq += v*v;
    }
    s = block_sum(s, tmp);
    sq = block_sum(sq, tmp);
    if (threadIdx.x == 0) {
        float m = s / LSEQ;
        float var = sq / LSEQ - m*m;
        if (var < 0.f) var = 0.f;
        mean[bc] = m;
        stdv[bc] = sqrtf(var + EPSV);
    }
}

// ---------------------------------------------------------------- embedding
__global__ __launch_bounds__(256) void embed_kernel(const float* __restrict__ x,
                                                    const float* __restrict__ token_w,
                                                    const float* __restrict__ time_w,
                                                    const float* __restrict__ mean,
                                                    const float* __restrict__ stdv,
                                                    float* __restrict__ h) {
    int bl = blockIdx.x;
    int b = bl >> 9, l = bl & 511;
    __shared__ float sxc[ENC_IN*3];
    if (threadIdx.x < ENC_IN*3) {
        int c = threadIdx.x / 3, k = threadIdx.x % 3;
        int lk = (l + k - 1) & 511;
        float v = x[((size_t)(b*LSEQ + lk))*ENC_IN + c];
        sxc[threadIdx.x] = (v - mean[b*ENC_IN + c]) / stdv[b*ENC_IN + c];
    }
    __syncthreads();
    #pragma unroll
    for (int i = 0; i < 3; i++) {
        int d = threadIdx.x + i*256;
        float acc = 0.f;
        const float* w = token_w + (size_t)d*21;
        #pragma unroll
        for (int t = 0; t < 21; t++) acc += sxc[t] * w[t];
        int d2 = d & ~1;
        float div = __expf((float)d2 * (-9.210340371976184f / (float)D_MODEL));
        float ang = (float)l * div;
        float pe = (d & 1) ? cosf(ang) : sinf(ang);
        float tm = ((float)l / (float)LSEQ) * time_w[d];
        h[(size_t)bl*D_MODEL + d] = acc + pe + tm;
    }
}

// ---------------------------------------------------------------- rmsnorm -> bf16
__global__ __launch_bounds__(256) void rmsnorm_bf16(const float* __restrict__ h,
                                                    const float* __restrict__ w,
                                                    __hip_bfloat16* __restrict__ xn) {
    size_t base = (size_t)blockIdx.x * D_MODEL;
    __shared__ float tmp[4];
    float ss = 0.f;
    for (int k = threadIdx.x; k < D_MODEL; k += 256) { float v = h[base+k]; ss += v*v; }
    ss = block_sum(ss, tmp);
    float inv = rsqrtf(ss / (float)D_MODEL + EPSV);
    for (int k = threadIdx.x; k < D_MODEL; k += 256)
        xn[base+k] = __float2bfloat16(h[base+k]*inv*w[k]);
}

// ---------------------------------------------------------------- bf16 MFMA GEMM
// C(M x N) = A(M x K, row-major bf16) @ Bw(N x K, row-major bf16)^T
// FUSE 0: plain f32 out.  FUSE 2: out = acc + res (residual add, res==C allowed)
template<int FUSE>
__global__ __launch_bounds__(256) void gemm_mfma(const __hip_bfloat16* __restrict__ A,
                                                 const __hip_bfloat16* __restrict__ Bw,
                                                 float* __restrict__ C, int ldc,
                                                 int K,
                                                 const float* __restrict__ res, int ldr) {
    __shared__ __align__(16) __hip_bfloat16 As[128*32];
    __shared__ __align__(16) __hip_bfloat16 Bs[128*32];
    int tid = threadIdx.x, lane = tid & 63, w = tid >> 6;
    int m0 = blockIdx.y * 128, n0 = blockIdx.x * 128;
    int wr = w >> 1, wc = w & 1;

    f32x4 acc[4][4];
    #pragma unroll
    for (int i = 0; i < 4; i++)
        #pragma unroll
        for (int j = 0; j < 4; j++) acc[i][j] = (f32x4){0.f,0.f,0.f,0.f};

    const unsigned char* Ab = (const unsigned char*)A;
    const unsigned char* Bb = (const unsigned char*)Bw;
    char* AsB = (char*)As;
    char* BsB = (char*)Bs;

    int c0 = tid, c1 = tid + 256;
    int r0 = c0 >> 2, cb0 = (c0 & 3) << 4;   // row, byte-col within 64B row (BK=32 bf16)
    int r1 = c1 >> 2, cb1 = (c1 & 3) << 4;
    int kq = lane >> 4, rr = lane & 15;

    for (int k0 = 0; k0 < K; k0 += 32) {
        size_t kb = (size_t)k0*2;
        __builtin_amdgcn_global_load_lds(
            (const __attribute__((address_space(1))) unsigned int*)(Ab + ((size_t)(m0+r0)*K)*2 + kb + cb0),
            (__attribute__((address_space(3))) unsigned int*)(AsB + c0*16), 16, 0, 0);
        __builtin_amdgcn_global_load_lds(
            (const __attribute__((address_space(1))) unsigned int*)(Ab + ((size_t)(m0+r1)*K)*2 + kb + cb1),
            (__attribute__((address_space(3))) unsigned int*)(AsB + c1*16), 16, 0, 0);
        __builtin_amdgcn_global_load_lds(
            (const __attribute__((address_space(1))) unsigned int*)(Bb + ((size_t)(n0+r0)*K)*2 + kb + cb0),
            (__attribute__((address_space(3))) unsigned int*)(BsB + c0*16), 16, 0, 0);
        __builtin_amdgcn_global_load_lds(
            (const __attribute__((address_space(1))) unsigned int*)(Bb + ((size_t)(n0+r1)*K)*2 + kb + cb1),
            (__attribute__((address_space(3))) unsigned int*)(BsB + c1*16), 16, 0, 0);
        __syncthreads();

        const bf16x8* Av = (const bf16x8*)As;
        const bf16x8* Bv = (const bf16x8*)Bs;
        bf16x8 af[4], bfr[4];
        #pragma unroll
        for (int mi = 0; mi < 4; mi++) af[mi]  = Av[(wr*64 + mi*16 + rr)*4 + kq];
        #pragma unroll
        for (int ni = 0; ni < 4; ni++) bfr[ni] = Bv[(wc*64 + ni*16 + rr)*4 + kq];
        #pragma unroll
        for (int mi = 0; mi < 4; mi++)
            #pragma unroll
            for (int ni = 0; ni < 4; ni++)
                acc[mi][ni] = __builtin_amdgcn_mfma_f32_16x16x32_bf16(af[mi], bfr[ni], acc[mi][ni], 0, 0, 0);
        __syncthreads();
    }

    #pragma unroll
    for (int mi = 0; mi < 4; mi++) {
        #pragma unroll
        for (int ni = 0; ni < 4; ni++) {
            #pragma unroll
            for (int r = 0; r < 4; r++) {
                int row = m0 + wr*64 + mi*16 + kq*4 + r;
                int col = n0 + wc*64 + ni*16 + rr;
                float v = acc[mi][ni][r];
                if (FUSE == 2) v += res[(size_t)row*ldr + col];
                C[(size_t)row*ldc + col] = v;
            }
        }
    }
}

// ---------------------------------------------------------------- generic fp32 GEMM (small ones)
#define BM 64
#define BN 64
#define BKT 16
template<int FUSE>
__global__ __launch_bounds__(256) void gemm_nt(const float* __restrict__ A, int lda,
                                               const float* __restrict__ W,
                                               float* __restrict__ C, int ldc,
                                               int M, int N, int K,
                                               const float* __restrict__ bias) {
    __shared__ float As[BKT][BM+4];
    __shared__ float Ws[BKT][BN+4];
    int tid = threadIdx.x;
    int tx = tid & 15, ty = tid >> 4;
    int m0 = blockIdx.y * BM, n0 = blockIdx.x * BN;
    float acc[4][4] = {};
    for (int k0 = 0; k0 < K; k0 += BKT) {
        #pragma unroll
        for (int i = 0; i < 4; i++) {
            int idx = tid + i*256;
            int r = idx >> 4, c = idx & 15;
            int m = m0 + r, k = k0 + c;
            As[c][r] = (m < M && k < K) ? A[(size_t)m*lda + k] : 0.f;
            int n = n0 + r;
            Ws[c][r] = (n < N && k < K) ? W[(size_t)n*K + k] : 0.f;
        }
        __syncthreads();
        #pragma unroll
        for (int k = 0; k < BKT; k++) {
            float4 a = *(const float4*)&As[k][ty*4];
            float4 b = *(const float4*)&Ws[k][tx*4];
            float av[4] = {a.x,a.y,a.z,a.w};
            float bv[4] = {b.x,b.y,b.z,b.w};
            #pragma unroll
            for (int i = 0; i < 4; i++)
                #pragma unroll
                for (int j = 0; j < 4; j++)
                    acc[i][j] += av[i]*bv[j];
        }
        __syncthreads();
    }
    #pragma unroll
    for (int i = 0; i < 4; i++) {
        int m = m0 + ty*4 + i; if (m >= M) continue;
        #pragma unroll
        for (int j = 0; j < 4; j++) {
            int n = n0 + tx*4 + j; if (n >= N) continue;
            float v = acc[i][j];
            if (FUSE == 1) { v += bias[n]; v = fmaxf(v, 0.f) + log1pf(__expf(-fabsf(v))); }
            C[(size_t)m*ldc + n] = v;
        }
    }
}

// ---------------------------------------------------------------- depthwise causal conv + SiLU
__global__ __launch_bounds__(256) void dwconv_silu(const float* __restrict__ xr,
                                                   const float* __restrict__ cw,
                                                   const float* __restrict__ cb,
                                                   float* __restrict__ u) {
    int idx = blockIdx.x*256 + threadIdx.x;
    if (idx >= ROWS*D_INNER) return;
    int d = idx % D_INNER;
    int t = idx / D_INNER;
    int l = t & 511, b = t >> 9;
    float acc = cb[d];
    #pragma unroll
    for (int k = 0; k < K_CONV; k++) {
        int ll = l - (K_CONV-1) + k;
        if (ll >= 0) acc += xr[((size_t)(b*LSEQ + ll))*(2*D_INNER) + d] * cw[d*K_CONV + k];
    }
    u[(size_t)t*D_INNER + d] = acc / (1.f + __expf(-acc));
}

// ---------------------------------------------------------------- selective scan, 3-phase chunked
// Phase 1: per (b,chunk,d): local scan (x0=0), store final state + sum(delta)
__global__ __launch_bounds__(256) void scan_p1(const float* __restrict__ u,
                                               const float* __restrict__ delta,
                                               const float* __restrict__ xdbl,
                                               const float* __restrict__ A_log,
                                               float* __restrict__ xfin,
                                               float* __restrict__ sumdlt) {
    int d = blockIdx.x*256 + threadIdx.x;
    int c = blockIdx.y, b = blockIdx.z;
    float A[N_STATE], xs[N_STATE];
    #pragma unroll
    for (int n = 0; n < N_STATE; n++) {
        A[n] = -__expf(A_log[d*N_STATE + n]);
        xs[n] = 0.f;
    }
    float sd = 0.f;
    int l0 = c*CL;
    for (int i = 0; i < CL; i++) {
        size_t base = (size_t)(b*LSEQ + l0 + i);
        float dlt = delta[base*D_INNER + d];
        float uu  = u[base*D_INNER + d];
        const float4* Bp = (const float4*)(xdbl + base*80 + DT_RANK);
        float4 B0 = Bp[0], B1 = Bp[1], B2 = Bp[2], B3 = Bp[3];
        float Bv[N_STATE] = {B0.x,B0.y,B0.z,B0.w,B1.x,B1.y,B1.z,B1.w,
                             B2.x,B2.y,B2.z,B2.w,B3.x,B3.y,B3.z,B3.w};
        float du = dlt*uu;
        sd += dlt;
        #pragma unroll
        for (int n = 0; n < N_STATE; n++)
            xs[n] = __expf(dlt*A[n])*xs[n] + du*Bv[n];
    }
    size_t j = ((size_t)(b*NC + c)*D_INNER + d);
    #pragma unroll
    for (int n = 0; n < N_STATE; n += 4)
        *(float4*)&xfin[j*N_STATE + n] = (float4){xs[n],xs[n+1],xs[n+2],xs[n+3]};
    sumdlt[j] = sd;
}

// Phase 2: sequential carry combine across chunks. thread per (b,d,n).
__global__ __launch_bounds__(256) void scan_p2(const float* __restrict__ xfin,
                                               const float* __restrict__ sumdlt,
                                               const float* __restrict__ A_log,
                                               float* __restrict__ carry) {
    int idx = blockIdx.x*256 + threadIdx.x;
    int n = idx & 15;
    int rest = idx >> 4;
    int d = rest % D_INNER;
    int b = rest / D_INNER;
    float A = -__expf(A_log[d*N_STATE + n]);
    float cr = 0.f;
    carry[((size_t)(b*NC + 0)*D_INNER + d)*N_STATE + n] = 0.f;
    for (int c = 1; c < NC; c++) {
        size_t j = (size_t)(b*NC + c - 1)*D_INNER + d;
        cr = __expf(A * sumdlt[j]) * cr + xfin[j*N_STATE + n];
        carry[((size_t)(b*NC + c)*D_INNER + d)*N_STATE + n] = cr;
    }
}

// Phase 3: re-scan chunk with carry-in, compute y, fuse u*Dp + gate, write bf16
__global__ __launch_bounds__(256) void scan_p3(const float* __restrict__ u,
                                               const float* __restrict__ delta,
                                               const float* __restrict__ xdbl,
                                               const float* __restrict__ A_log,
                                               const float* __restrict__ Dp,
                                               const float* __restrict__ carry,
                                               const float* __restrict__ xr,
                                               __hip_bfloat16* __restrict__ ygate) {
    int d = blockIdx.x*256 + threadIdx.x;
    int c = blockIdx.y, b = blockIdx.z;
    float A[N_STATE], xs[N_STATE];
    size_t jc = ((size_t)(b*NC + c)*D_INNER + d)*N_STATE;
    #pragma unroll
    for (int n = 0; n < N_STATE; n++) {
        A[n] = -__expf(A_log[d*N_STATE + n]);
        xs[n] = carry[jc + n];
    }
    float Dv = Dp[d];
    int l0 = c*CL;
    for (int i = 0; i < CL; i++) {
        size_t base = (size_t)(b*LSEQ + l0 + i);
        float dlt = delta[base*D_INNER + d];
        float uu  = u[base*D_INNER + d];
        const float4* Bp = (const float4*)(xdbl + base*80 + DT_RANK);
        float4 B0 = Bp[0], B1 = Bp[1], B2 = Bp[2], B3 = Bp[3];
        float4 C0 = Bp[4], C1 = Bp[5], C2 = Bp[6], C3 = Bp[7];
        float Bv[N_STATE] = {B0.x,B0.y,B0.z,B0.w,B1.x,B1.y,B1.z,B1.w,
                             B2.x,B2.y,B2.z,B2.w,B3.x,B3.y,B3.z,B3.w};
        float Cv[N_STATE] = {C0.x,C0.y,C0.z,C0.w,C1.x,C1.y,C1.z,C1.w,
                             C2.x,C2.y,C2.z,C2.w,C3.x,C3.y,C3.z,C3.w};
        float du = dlt*uu;
        float acc = 0.f;
        #pragma unroll
        for (int n = 0; n < N_STATE; n++) {
            xs[n] = __expf(dlt*A[n])*xs[n] + du*Bv[n];
            acc += xs[n]*Cv[n];
        }
        float y = acc + uu*Dv;
        float r = xr[base*(2*D_INNER) + D_INNER + d];
        float g = y * (r / (1.f + __expf(-r)));
        ygate[base*D_INNER + d] = __float2bfloat16(g);
    }
}

// ---------------------------------------------------------------- final norm + head + de-norm
__global__ __launch_bounds__(256) void final_kernel(const float* __restrict__ h,
                                                    const float* __restrict__ fnw,
                                                    const float* __restrict__ out_w,
                                                    const float* __restrict__ mean,
                                                    const float* __restrict__ stdv,
                                                    float* __restrict__ out) {
    int bid = blockIdx.x;
    int b = bid / PRED_LEN, lo = bid % PRED_LEN;
    int l = LSEQ - PRED_LEN + lo;
    const float* row = h + ((size_t)(b*LSEQ + l))*D_MODEL;
    __shared__ float tmp[4];
    float ss = 0.f;
    for (int k = threadIdx.x; k < D_MODEL; k += 256) { float v = row[k]; ss += v*v; }
    ss = block_sum(ss, tmp);
    float inv = rsqrtf(ss / (float)D_MODEL + EPSV);
    float acc[C_OUT] = {};
    for (int k = threadIdx.x; k < D_MODEL; k += 256) {
        float hn = row[k]*fnw[k];
        #pragma unroll
        for (int c = 0; c < C_OUT; c++) acc[c] += hn*out_w[c*D_MODEL + k];
    }
    #pragma unroll
    for (int c = 0; c < C_OUT; c++) {
        float s = block_sum(acc[c], tmp);
        if (threadIdx.x == 0)
            out[((size_t)(b*PRED_LEN + lo))*C_OUT + c] = s*inv*stdv[b*ENC_IN + c] + mean[b*ENC_IN + c];
    }
}

// ---------------------------------------------------------------- launch
extern "C" void kernel_launch(void* const* d_in, const int* in_sizes, int n_in,
                              void* d_out, int out_size, void* d_ws, size_t ws_size,
                              hipStream_t stream) {
    const float* x        = (const float*)d_in[0];
    const float* token_w  = (const float*)d_in[1];
    const float* time_w   = (const float*)d_in[2];
    const float* norm_w   = (const float*)d_in[3];
    const float* in_w     = (const float*)d_in[4];
    const float* conv_w   = (const float*)d_in[5];
    const float* conv_b   = (const float*)d_in[6];
    const float* xproj_w  = (const float*)d_in[7];
    const float* dtproj_w = (const float*)d_in[8];
    const float* dtproj_b = (const float*)d_in[9];
    const float* A_log    = (const float*)d_in[10];
    const float* Dp       = (const float*)d_in[11];
    const float* outproj_w= (const float*)d_in[12];
    const float* final_nw = (const float*)d_in[13];
    const float* out_w    = (const float*)d_in[14];
    float* out = (float*)d_out;

    float* ws   = (float*)d_ws;
    float* mean = ws;
    float* stdv = ws + 64;
    float* h    = ws + 128;
    float* xr   = h    + (size_t)ROWS*D_MODEL;
    float* u    = xr   + (size_t)ROWS*2*D_INNER;
    float* xdbl = u    + (size_t)ROWS*D_INNER;
    float* delta= xdbl + (size_t)ROWS*80;
    float* xfin = delta+ (size_t)ROWS*D_INNER;
    float* carry= xfin + (size_t)BSZ*NC*D_INNER*N_STATE;
    float* sumd = carry+ (size_t)BSZ*NC*D_INNER*N_STATE;
    float* fend = sumd + (size_t)BSZ*NC*D_INNER;
    __hip_bfloat16* xn_bf  = (__hip_bfloat16*)fend;
    __hip_bfloat16* ygate  = xn_bf + (size_t)ROWS*D_MODEL;
    __hip_bfloat16* inw_bf = ygate + (size_t)ROWS*D_INNER;
    __hip_bfloat16* outw_bf= inw_bf + (size_t)E_LAYERS*2*D_INNER*D_MODEL;
    // total ≈ 161 MB

    // convert weights to bf16 (once per call)
    {
        int n1 = E_LAYERS*2*D_INNER*D_MODEL;
        cvt_bf16<<<(n1+255)/256, 256, 0, stream>>>(in_w, inw_bf, n1);
        int n2 = E_LAYERS*D_MODEL*D_INNER;
        cvt_bf16<<<(n2+255)/256, 256, 0, stream>>>(outproj_w, outw_bf, n2);
    }

    stats_kernel<<<BSZ*ENC_IN, 256, 0, stream>>>(x, mean, stdv);
    embed_kernel<<<ROWS, 256, 0, stream>>>(x, token_w, time_w, mean, stdv, h);

    for (int e = 0; e < E_LAYERS; e++) {
        rmsnorm_bf16<<<ROWS, 256, 0, stream>>>(h, norm_w + e*D_MODEL, xn_bf);
        gemm_mfma<0><<<dim3(2*D_INNER/128, ROWS/128), 256, 0, stream>>>(
            xn_bf, inw_bf + (size_t)e*2*D_INNER*D_MODEL, xr, 2*D_INNER, D_MODEL, nullptr, 0);
        dwconv_silu<<<(ROWS*D_INNER + 255)/256, 256, 0, stream>>>(
            xr, conv_w + (size_t)e*D_INNER*K_CONV, conv_b + e*D_INNER, u);
        gemm_nt<0><<<dim3((80 + BN-1)/BN, ROWS/BM), 256, 0, stream>>>(
            u, D_INNER, xproj_w + (size_t)e*80*D_INNER, xdbl, 80,
            ROWS, 80, D_INNER, nullptr);
        gemm_nt<1><<<dim3(D_INNER/BN, ROWS/BM), 256, 0, stream>>>(
            xdbl, 80, dtproj_w + (size_t)e*D_INNER*DT_RANK, delta, D_INNER,
            ROWS, D_INNER, DT_RANK, dtproj_b + e*D_INNER);
        const float* Alog_e = A_log + (size_t)e*D_INNER*N_STATE;
        scan_p1<<<dim3(D_INNER/256, NC, BSZ), 256, 0, stream>>>(
            u, delta, xdbl, Alog_e, xfin, sumd);
        scan_p2<<<(BSZ*D_INNER*N_STATE)/256, 256, 0, stream>>>(
            xfin, sumd, Alog_e, carry);
        scan_p3<<<dim3(D_INNER/256, NC, BSZ), 256, 0, stream>>>(
            u, delta, xdbl, Alog_e, Dp + (size_t)e*D_INNER, carry, xr, ygate);
        gemm_mfma<2><<<dim3(D_MODEL/128, ROWS/128), 256, 0, stream>>>(
            ygate, outw_bf + (size_t)e*D_MODEL*D_INNER, h, D_MODEL, D_INNER, h, D_MODEL);
    }

    final_kernel<<<BSZ*PRED_LEN, 256, 0, stream>>>(h, final_nw, out_w, mean, stdv, out);
}

// Round 3
// 512.148 us; speedup vs baseline: 4.6602x; 1.6957x over previous
//
#include <hip/hip_runtime.h>
#include <hip/hip_bf16.h>
#include <math.h>

// Problem constants
#define BSZ 8
#define LSEQ 512
#define ENC_IN 7
#define D_MODEL 768
#define D_INNER 1536
#define DT_RANK 48
#define N_STATE 16
#define K_CONV 4
#define E_LAYERS 2
#define C_OUT 7
#define PRED_LEN 96
#define EPSV 1e-5f
#define XN 80
#define KSPLIT 4

#define ROWS (BSZ*LSEQ)            // 4096
#define NC 8                       // scan chunks
#define CL (LSEQ/NC)               // 64 steps per chunk

typedef __bf16 bf16x8 __attribute__((ext_vector_type(8)));
typedef float  f32x4  __attribute__((ext_vector_type(4)));

// ---------------------------------------------------------------- utilities
__device__ __forceinline__ float block_sum(float v, float* tmp) {
    #pragma unroll
    for (int off = 32; off > 0; off >>= 1) v += __shfl_down(v, off);
    int lane = threadIdx.x & 63, wid = threadIdx.x >> 6;
    __syncthreads();
    if (lane == 0) tmp[wid] = v;
    __syncthreads();
    return tmp[0] + tmp[1] + tmp[2] + tmp[3];
}

// ---------------------------------------------------------------- f32 -> bf16 convert
__global__ __launch_bounds__(256) void cvt_bf16(const float* __restrict__ in,
                                                __hip_bfloat16* __restrict__ out, int n) {
    int i = blockIdx.x*256 + threadIdx.x;
    if (i < n) out[i] = __float2bfloat16(in[i]);
}

// pack src(rows x sld) cols[0:kvalid) into bf16 dst(rows x dld), zero-pad rest
__global__ __launch_bounds__(256) void pack_pad(const float* __restrict__ src, int sld, int kvalid,
                                                __hip_bfloat16* __restrict__ dst, int dld, int rows) {
    int i = blockIdx.x*256 + threadIdx.x;
    int r = i / dld, c = i % dld;
    if (r < rows)
        dst[i] = __float2bfloat16(c < kvalid ? src[(size_t)r*sld + c] : 0.f);
}

// ---------------------------------------------------------------- stats (RevIN)
__global__ __launch_bounds__(256) void stats_kernel(const float* __restrict__ x,
                                                    float* __restrict__ mean,
                                                    float* __restrict__ stdv) {
    int bc = blockIdx.x;
    int b = bc / ENC_IN, c = bc % ENC_IN;
    __shared__ float tmp[4];
    float s = 0.f, sq = 0.f;
    for (int l = threadIdx.x; l < LSEQ; l += 256) {
        float v = x[((size_t)(b*LSEQ + l))*ENC_IN + c];
        s += v; sq += v*v;
    }
    s = block_sum(s, tmp);
    sq = block_sum(sq, tmp);
    if (threadIdx.x == 0) {
        float m = s / LSEQ;
        float var = sq / LSEQ - m*m;
        if (var < 0.f) var = 0.f;
        mean[bc] = m;
        stdv[bc] = sqrtf(var + EPSV);
    }
}

// ---------------------------------------------------------------- embedding
__global__ __launch_bounds__(256) void embed_kernel(const float* __restrict__ x,
                                                    const float* __restrict__ token_w,
                                                    const float* __restrict__ time_w,
                                                    const float* __restrict__ mean,
                                                    const float* __restrict__ stdv,
                                                    float* __restrict__ h) {
    int bl = blockIdx.x;
    int b = bl >> 9, l = bl & 511;
    __shared__ float sxc[ENC_IN*3];
    if (threadIdx.x < ENC_IN*3) {
        int c = threadIdx.x / 3, k = threadIdx.x % 3;
        int lk = (l + k - 1) & 511;
        float v = x[((size_t)(b*LSEQ + lk))*ENC_IN + c];
        sxc[threadIdx.x] = (v - mean[b*ENC_IN + c]) / stdv[b*ENC_IN + c];
    }
    __syncthreads();
    #pragma unroll
    for (int i = 0; i < 3; i++) {
        int d = threadIdx.x + i*256;
        float acc = 0.f;
        const float* w = token_w + (size_t)d*21;
        #pragma unroll
        for (int t = 0; t < 21; t++) acc += sxc[t] * w[t];
        int d2 = d & ~1;
        float div = __expf((float)d2 * (-9.210340371976184f / (float)D_MODEL));
        float ang = (float)l * div;
        float pe = (d & 1) ? cosf(ang) : sinf(ang);
        float tm = ((float)l / (float)LSEQ) * time_w[d];
        h[(size_t)bl*D_MODEL + d] = acc + pe + tm;
    }
}

// ---------------------------------------------------------------- rmsnorm -> bf16
__global__ __launch_bounds__(256) void rmsnorm_bf16(const float* __restrict__ h,
                                                    const float* __restrict__ w,
                                                    __hip_bfloat16* __restrict__ xn) {
    size_t base = (size_t)blockIdx.x * D_MODEL;
    __shared__ float tmp[4];
    float ss = 0.f;
    for (int k = threadIdx.x; k < D_MODEL; k += 256) { float v = h[base+k]; ss += v*v; }
    ss = block_sum(ss, tmp);
    float inv = rsqrtf(ss / (float)D_MODEL + EPSV);
    for (int k = threadIdx.x; k < D_MODEL; k += 256)
        xn[base+k] = __float2bfloat16(h[base+k]*inv*w[k]);
}

// ---------------------------------------------------------------- bf16 MFMA GEMM (128x128 tile, BK=32)
// C(M x N) = A(M x K) @ Bw(N x K)^T.  XOR-swizzled LDS (chunk ^= (row>>1)&3).
// FUSE 0: plain   FUSE 1: softplus(acc+bias[n])   FUSE 2: acc + res
template<int FUSE>
__global__ __launch_bounds__(256) void gemm_mfma(const __hip_bfloat16* __restrict__ A,
                                                 const __hip_bfloat16* __restrict__ Bw,
                                                 float* __restrict__ C, int ldc,
                                                 int K,
                                                 const float* __restrict__ bias,
                                                 const float* __restrict__ res, int ldr) {
    __shared__ __align__(16) __hip_bfloat16 As[128*32];
    __shared__ __align__(16) __hip_bfloat16 Bs[128*32];
    int tid = threadIdx.x, lane = tid & 63, w = tid >> 6;
    int m0 = blockIdx.y * 128, n0 = blockIdx.x * 128;
    int wr = w >> 1, wc = w & 1;
    int kq = lane >> 4, rr = lane & 15;

    f32x4 acc[4][4];
    #pragma unroll
    for (int i = 0; i < 4; i++)
        #pragma unroll
        for (int j = 0; j < 4; j++) acc[i][j] = (f32x4){0.f,0.f,0.f,0.f};

    const char* Ab = (const char*)A;
    const char* Bb = (const char*)Bw;
    char* AsB = (char*)As;
    char* BsB = (char*)Bs;

    int c0 = tid, c1 = tid + 256;
    int r0 = c0 >> 2, q0 = (c0 & 3) ^ ((r0 >> 1) & 3);   // swizzled chunk
    int r1 = c1 >> 2, q1 = (c1 & 3) ^ ((r1 >> 1) & 3);
    int sw = (kq ^ ((rr >> 1) & 3)) * 16;                // swizzled read byte offset

    for (int k0 = 0; k0 < K; k0 += 32) {
        __builtin_amdgcn_global_load_lds(
            (const __attribute__((address_space(1))) unsigned int*)(Ab + ((size_t)(m0+r0)*K + k0 + q0*8)*2),
            (__attribute__((address_space(3))) unsigned int*)(AsB + c0*16), 16, 0, 0);
        __builtin_amdgcn_global_load_lds(
            (const __attribute__((address_space(1))) unsigned int*)(Ab + ((size_t)(m0+r1)*K + k0 + q1*8)*2),
            (__attribute__((address_space(3))) unsigned int*)(AsB + c1*16), 16, 0, 0);
        __builtin_amdgcn_global_load_lds(
            (const __attribute__((address_space(1))) unsigned int*)(Bb + ((size_t)(n0+r0)*K + k0 + q0*8)*2),
            (__attribute__((address_space(3))) unsigned int*)(BsB + c0*16), 16, 0, 0);
        __builtin_amdgcn_global_load_lds(
            (const __attribute__((address_space(1))) unsigned int*)(Bb + ((size_t)(n0+r1)*K + k0 + q1*8)*2),
            (__attribute__((address_space(3))) unsigned int*)(BsB + c1*16), 16, 0, 0);
        __syncthreads();

        bf16x8 af[4], bfr[4];
        #pragma unroll
        for (int mi = 0; mi < 4; mi++) af[mi]  = *(const bf16x8*)(AsB + (wr*64 + mi*16 + rr)*64 + sw);
        #pragma unroll
        for (int ni = 0; ni < 4; ni++) bfr[ni] = *(const bf16x8*)(BsB + (wc*64 + ni*16 + rr)*64 + sw);
        #pragma unroll
        for (int mi = 0; mi < 4; mi++)
            #pragma unroll
            for (int ni = 0; ni < 4; ni++)
                acc[mi][ni] = __builtin_amdgcn_mfma_f32_16x16x32_bf16(af[mi], bfr[ni], acc[mi][ni], 0, 0, 0);
        __syncthreads();
    }

    #pragma unroll
    for (int mi = 0; mi < 4; mi++) {
        #pragma unroll
        for (int ni = 0; ni < 4; ni++) {
            #pragma unroll
            for (int r = 0; r < 4; r++) {
                int row = m0 + wr*64 + mi*16 + kq*4 + r;
                int col = n0 + wc*64 + ni*16 + rr;
                float v = acc[mi][ni][r];
                if (FUSE == 1) { v += bias[col]; v = fmaxf(v, 0.f) + log1pf(__expf(-fabsf(v))); }
                if (FUSE == 2) v += res[(size_t)row*ldr + col];
                C[(size_t)row*ldc + col] = v;
            }
        }
    }
}

// ---------------------------------------------------------------- xproj MFMA: C(4096 x 80) += A @ W^T, split-K
// BM=64, BK=64, 4 waves (one 16-row m-frag each), 5 n-frags. atomicAdd epilogue.
__global__ __launch_bounds__(256) void gemm_xproj(const __hip_bfloat16* __restrict__ A,
                                                  const __hip_bfloat16* __restrict__ W,
                                                  float* __restrict__ C) {
    __shared__ __align__(16) __hip_bfloat16 As[64*64];   // 8 KB
    __shared__ __align__(16) __hip_bfloat16 Bs[96*64];   // 12 KB (80 pad to 96)
    int tid = threadIdx.x, lane = tid & 63, w = tid >> 6;
    int m0 = blockIdx.x * 64;
    int k0 = blockIdx.y * (D_INNER / KSPLIT);
    int kq = lane >> 4, rr = lane & 15;
    f32x4 acc[5];
    #pragma unroll
    for (int i = 0; i < 5; i++) acc[i] = (f32x4){0.f,0.f,0.f,0.f};
    const char* Ab = (const char*)A;
    const char* Wb = (const char*)W;
    char* AsB = (char*)As;
    char* BsB = (char*)Bs;

    for (int kk = k0; kk < k0 + D_INNER/KSPLIT; kk += 64) {
        #pragma unroll
        for (int cA = 0; cA < 2; cA++) {
            int idx = cA*256 + tid;
            int r = idx >> 3, q = (idx & 7) ^ (r & 7);
            __builtin_amdgcn_global_load_lds(
                (const __attribute__((address_space(1))) unsigned int*)(Ab + ((size_t)(m0+r)*D_INNER + kk + q*8)*2),
                (__attribute__((address_space(3))) unsigned int*)(AsB + idx*16), 16, 0, 0);
        }
        #pragma unroll
        for (int cB = 0; cB < 3; cB++) {
            int idx = cB*256 + tid;
            int r = idx >> 3, q = (idx & 7) ^ (r & 7);
            int rs = r < XN ? r : XN-1;
            __builtin_amdgcn_global_load_lds(
                (const __attribute__((address_space(1))) unsigned int*)(Wb + ((size_t)rs*D_INNER + kk + q*8)*2),
                (__attribute__((address_space(3))) unsigned int*)(BsB + idx*16), 16, 0, 0);
        }
        __syncthreads();
        #pragma unroll
        for (int kh = 0; kh < 2; kh++) {
            bf16x8 a = *(const bf16x8*)(AsB + (w*16 + rr)*128 + (((kh*4 + kq) ^ (rr & 7)))*16);
            #pragma unroll
            for (int ni = 0; ni < 5; ni++) {
                bf16x8 b = *(const bf16x8*)(BsB + (ni*16 + rr)*128 + (((kh*4 + kq) ^ (rr & 7)))*16);
                acc[ni] = __builtin_amdgcn_mfma_f32_16x16x32_bf16(a, b, acc[ni], 0, 0, 0);
            }
        }
        __syncthreads();
    }
    #pragma unroll
    for (int ni = 0; ni < 5; ni++)
        #pragma unroll
        for (int r = 0; r < 4; r++) {
            int row = m0 + w*16 + kq*4 + r;
            int col = ni*16 + rr;
            atomicAdd(&C[(size_t)row*XN + col], acc[ni][r]);
        }
}

// ---------------------------------------------------------------- depthwise causal conv + SiLU (+ bf16 copy)
__global__ __launch_bounds__(256) void dwconv_silu(const float* __restrict__ xr,
                                                   const float* __restrict__ cw,
                                                   const float* __restrict__ cb,
                                                   float* __restrict__ u,
                                                   __hip_bfloat16* __restrict__ u_bf) {
    int idx = blockIdx.x*256 + threadIdx.x;
    if (idx >= ROWS*D_INNER) return;
    int d = idx % D_INNER;
    int t = idx / D_INNER;
    int l = t & 511, b = t >> 9;
    float acc = cb[d];
    #pragma unroll
    for (int k = 0; k < K_CONV; k++) {
        int ll = l - (K_CONV-1) + k;
        if (ll >= 0) acc += xr[((size_t)(b*LSEQ + ll))*(2*D_INNER) + d] * cw[d*K_CONV + k];
    }
    float v = acc / (1.f + __expf(-acc));
    u[(size_t)t*D_INNER + d] = v;
    u_bf[(size_t)t*D_INNER + d] = __float2bfloat16(v);
}

// ---------------------------------------------------------------- selective scan, 3-phase chunked
__global__ __launch_bounds__(256) void scan_p1(const float* __restrict__ u,
                                               const float* __restrict__ delta,
                                               const float* __restrict__ xdbl,
                                               const float* __restrict__ A_log,
                                               float* __restrict__ xfin,
                                               float* __restrict__ sumdlt) {
    int d = blockIdx.x*256 + threadIdx.x;
    int c = blockIdx.y, b = blockIdx.z;
    float A[N_STATE], xs[N_STATE];
    #pragma unroll
    for (int n = 0; n < N_STATE; n++) {
        A[n] = -__expf(A_log[d*N_STATE + n]);
        xs[n] = 0.f;
    }
    float sd = 0.f;
    int l0 = c*CL;
    for (int i = 0; i < CL; i++) {
        size_t base = (size_t)(b*LSEQ + l0 + i);
        float dlt = delta[base*D_INNER + d];
        float uu  = u[base*D_INNER + d];
        const float4* Bp = (const float4*)(xdbl + base*80 + DT_RANK);
        float4 B0 = Bp[0], B1 = Bp[1], B2 = Bp[2], B3 = Bp[3];
        float Bv[N_STATE] = {B0.x,B0.y,B0.z,B0.w,B1.x,B1.y,B1.z,B1.w,
                             B2.x,B2.y,B2.z,B2.w,B3.x,B3.y,B3.z,B3.w};
        float du = dlt*uu;
        sd += dlt;
        #pragma unroll
        for (int n = 0; n < N_STATE; n++)
            xs[n] = __expf(dlt*A[n])*xs[n] + du*Bv[n];
    }
    size_t j = ((size_t)(b*NC + c)*D_INNER + d);
    #pragma unroll
    for (int n = 0; n < N_STATE; n += 4)
        *(float4*)&xfin[j*N_STATE + n] = (float4){xs[n],xs[n+1],xs[n+2],xs[n+3]};
    sumdlt[j] = sd;
}

__global__ __launch_bounds__(256) void scan_p2(const float* __restrict__ xfin,
                                               const float* __restrict__ sumdlt,
                                               const float* __restrict__ A_log,
                                               float* __restrict__ carry) {
    int idx = blockIdx.x*256 + threadIdx.x;
    int n = idx & 15;
    int rest = idx >> 4;
    int d = rest % D_INNER;
    int b = rest / D_INNER;
    float A = -__expf(A_log[d*N_STATE + n]);
    float cr = 0.f;
    carry[((size_t)(b*NC + 0)*D_INNER + d)*N_STATE + n] = 0.f;
    for (int c = 1; c < NC; c++) {
        size_t j = (size_t)(b*NC + c - 1)*D_INNER + d;
        cr = __expf(A * sumdlt[j]) * cr + xfin[j*N_STATE + n];
        carry[((size_t)(b*NC + c)*D_INNER + d)*N_STATE + n] = cr;
    }
}

__global__ __launch_bounds__(256) void scan_p3(const float* __restrict__ u,
                                               const float* __restrict__ delta,
                                               const float* __restrict__ xdbl,
                                               const float* __restrict__ A_log,
                                               const float* __restrict__ Dp,
                                               const float* __restrict__ carry,
                                               const float* __restrict__ xr,
                                               __hip_bfloat16* __restrict__ ygate) {
    int d = blockIdx.x*256 + threadIdx.x;
    int c = blockIdx.y, b = blockIdx.z;
    float A[N_STATE], xs[N_STATE];
    size_t jc = ((size_t)(b*NC + c)*D_INNER + d)*N_STATE;
    #pragma unroll
    for (int n = 0; n < N_STATE; n++) {
        A[n] = -__expf(A_log[d*N_STATE + n]);
        xs[n] = carry[jc + n];
    }
    float Dv = Dp[d];
    int l0 = c*CL;
    for (int i = 0; i < CL; i++) {
        size_t base = (size_t)(b*LSEQ + l0 + i);
        float dlt = delta[base*D_INNER + d];
        float uu  = u[base*D_INNER + d];
        const float4* Bp = (const float4*)(xdbl + base*80 + DT_RANK);
        float4 B0 = Bp[0], B1 = Bp[1], B2 = Bp[2], B3 = Bp[3];
        float4 C0 = Bp[4], C1 = Bp[5], C2 = Bp[6], C3 = Bp[7];
        float Bv[N_STATE] = {B0.x,B0.y,B0.z,B0.w,B1.x,B1.y,B1.z,B1.w,
                             B2.x,B2.y,B2.z,B2.w,B3.x,B3.y,B3.z,B3.w};
        float Cv[N_STATE] = {C0.x,C0.y,C0.z,C0.w,C1.x,C1.y,C1.z,C1.w,
                             C2.x,C2.y,C2.z,C2.w,C3.x,C3.y,C3.z,C3.w};
        float du = dlt*uu;
        float acc = 0.f;
        #pragma unroll
        for (int n = 0; n < N_STATE; n++) {
            xs[n] = __expf(dlt*A[n])*xs[n] + du*Bv[n];
            acc += xs[n]*Cv[n];
        }
        float y = acc + uu*Dv;
        float r = xr[base*(2*D_INNER) + D_INNER + d];
        float g = y * (r / (1.f + __expf(-r)));
        ygate[base*D_INNER + d] = __float2bfloat16(g);
    }
}

// ---------------------------------------------------------------- final norm + head + de-norm
__global__ __launch_bounds__(256) void final_kernel(const float* __restrict__ h,
                                                    const float* __restrict__ fnw,
                                                    const float* __restrict__ out_w,
                                                    const float* __restrict__ mean,
                                                    const float* __restrict__ stdv,
                                                    float* __restrict__ out) {
    int bid = blockIdx.x;
    int b = bid / PRED_LEN, lo = bid % PRED_LEN;
    int l = LSEQ - PRED_LEN + lo;
    const float* row = h + ((size_t)(b*LSEQ + l))*D_MODEL;
    __shared__ float tmp[4];
    float ss = 0.f;
    for (int k = threadIdx.x; k < D_MODEL; k += 256) { float v = row[k]; ss += v*v; }
    ss = block_sum(ss, tmp);
    float inv = rsqrtf(ss / (float)D_MODEL + EPSV);
    float acc[C_OUT] = {};
    for (int k = threadIdx.x; k < D_MODEL; k += 256) {
        float hn = row[k]*fnw[k];
        #pragma unroll
        for (int c = 0; c < C_OUT; c++) acc[c] += hn*out_w[c*D_MODEL + k];
    }
    #pragma unroll
    for (int c = 0; c < C_OUT; c++) {
        float s = block_sum(acc[c], tmp);
        if (threadIdx.x == 0)
            out[((size_t)(b*PRED_LEN + lo))*C_OUT + c] = s*inv*stdv[b*ENC_IN + c] + mean[b*ENC_IN + c];
    }
}

// ---------------------------------------------------------------- launch
extern "C" void kernel_launch(void* const* d_in, const int* in_sizes, int n_in,
                              void* d_out, int out_size, void* d_ws, size_t ws_size,
                              hipStream_t stream) {
    const float* x        = (const float*)d_in[0];
    const float* token_w  = (const float*)d_in[1];
    const float* time_w   = (const float*)d_in[2];
    const float* norm_w   = (const float*)d_in[3];
    const float* in_w     = (const float*)d_in[4];
    const float* conv_w   = (const float*)d_in[5];
    const float* conv_b   = (const float*)d_in[6];
    const float* xproj_w  = (const float*)d_in[7];
    const float* dtproj_w = (const float*)d_in[8];
    const float* dtproj_b = (const float*)d_in[9];
    const float* A_log    = (const float*)d_in[10];
    const float* Dp       = (const float*)d_in[11];
    const float* outproj_w= (const float*)d_in[12];
    const float* final_nw = (const float*)d_in[13];
    const float* out_w    = (const float*)d_in[14];
    float* out = (float*)d_out;

    float* ws   = (float*)d_ws;
    float* mean = ws;
    float* stdv = ws + 64;
    float* h    = ws + 128;
    float* xr   = h    + (size_t)ROWS*D_MODEL;
    float* u    = xr   + (size_t)ROWS*2*D_INNER;
    float* xdbl = u    + (size_t)ROWS*D_INNER;
    float* delta= xdbl + (size_t)ROWS*XN;
    float* xfin = delta+ (size_t)ROWS*D_INNER;
    float* carry= xfin + (size_t)BSZ*NC*D_INNER*N_STATE;
    float* sumd = carry+ (size_t)BSZ*NC*D_INNER*N_STATE;
    float* fend = sumd + (size_t)BSZ*NC*D_INNER;
    __hip_bfloat16* xn_bf  = (__hip_bfloat16*)fend;
    __hip_bfloat16* ygate  = xn_bf + (size_t)ROWS*D_MODEL;
    __hip_bfloat16* inw_bf = ygate + (size_t)ROWS*D_INNER;
    __hip_bfloat16* outw_bf= inw_bf + (size_t)E_LAYERS*2*D_INNER*D_MODEL;
    __hip_bfloat16* xpw_bf = outw_bf+ (size_t)E_LAYERS*D_MODEL*D_INNER;
    __hip_bfloat16* u_bf   = xpw_bf + (size_t)E_LAYERS*XN*D_INNER;
    __hip_bfloat16* xdbl_bf= u_bf   + (size_t)ROWS*D_INNER;          // 4096 x 64
    __hip_bfloat16* dtw_bf = xdbl_bf+ (size_t)ROWS*64;               // 1536 x 64

    // convert weights to bf16 (once per call)
    {
        int n1 = E_LAYERS*2*D_INNER*D_MODEL;
        cvt_bf16<<<(n1+255)/256, 256, 0, stream>>>(in_w, inw_bf, n1);
        int n2 = E_LAYERS*D_MODEL*D_INNER;
        cvt_bf16<<<(n2+255)/256, 256, 0, stream>>>(outproj_w, outw_bf, n2);
        int n3 = E_LAYERS*XN*D_INNER;
        cvt_bf16<<<(n3+255)/256, 256, 0, stream>>>(xproj_w, xpw_bf, n3);
    }

    stats_kernel<<<BSZ*ENC_IN, 256, 0, stream>>>(x, mean, stdv);
    embed_kernel<<<ROWS, 256, 0, stream>>>(x, token_w, time_w, mean, stdv, h);

    for (int e = 0; e < E_LAYERS; e++) {
        rmsnorm_bf16<<<ROWS, 256, 0, stream>>>(h, norm_w + e*D_MODEL, xn_bf);
        gemm_mfma<0><<<dim3(2*D_INNER/128, ROWS/128), 256, 0, stream>>>(
            xn_bf, inw_bf + (size_t)e*2*D_INNER*D_MODEL, xr, 2*D_INNER, D_MODEL,
            nullptr, nullptr, 0);
        dwconv_silu<<<(ROWS*D_INNER + 255)/256, 256, 0, stream>>>(
            xr, conv_w + (size_t)e*D_INNER*K_CONV, conv_b + e*D_INNER, u, u_bf);
        hipMemsetAsync(xdbl, 0, (size_t)ROWS*XN*sizeof(float), stream);
        gemm_xproj<<<dim3(ROWS/64, KSPLIT), 256, 0, stream>>>(
            u_bf, xpw_bf + (size_t)e*XN*D_INNER, xdbl);
        pack_pad<<<(ROWS*64+255)/256, 256, 0, stream>>>(xdbl, XN, DT_RANK, xdbl_bf, 64, ROWS);
        pack_pad<<<(D_INNER*64+255)/256, 256, 0, stream>>>(
            dtproj_w + (size_t)e*D_INNER*DT_RANK, DT_RANK, DT_RANK, dtw_bf, 64, D_INNER);
        gemm_mfma<1><<<dim3(D_INNER/128, ROWS/128), 256, 0, stream>>>(
            xdbl_bf, dtw_bf, delta, D_INNER, 64,
            dtproj_b + e*D_INNER, nullptr, 0);
        const float* Alog_e = A_log + (size_t)e*D_INNER*N_STATE;
        scan_p1<<<dim3(D_INNER/256, NC, BSZ), 256, 0, stream>>>(
            u, delta, xdbl, Alog_e, xfin, sumd);
        scan_p2<<<(BSZ*D_INNER*N_STATE)/256, 256, 0, stream>>>(
            xfin, sumd, Alog_e, carry);
        scan_p3<<<dim3(D_INNER/256, NC, BSZ), 256, 0, stream>>>(
            u, delta, xdbl, Alog_e, Dp + (size_t)e*D_INNER, carry, xr, ygate);
        gemm_mfma<2><<<dim3(D_MODEL/128, ROWS/128), 256, 0, stream>>>(
            ygate, outw_bf + (size_t)e*D_MODEL*D_INNER, h, D_MODEL, D_INNER,
            nullptr, h, D_MODEL);
    }

    final_kernel<<<BSZ*PRED_LEN, 256, 0, stream>>>(h, final_nw, out_w, mean, stdv, out);
}